// Round 1
// baseline (782.462 us; speedup 1.0000x reference)
//
#include <hip/hip_runtime.h>
#include <math.h>

#define PI_F 3.14159265358979323846f

__device__ __forceinline__ float sigmoidf_(float x){ return 1.0f/(1.0f+__expf(-x)); }
__device__ __forceinline__ float softplusf_(float x){ return (x>20.f)? x : log1pf(__expf(x)); }

// ---------------------------------------------------------------------------
// GEMM1: C1[16384 x 896] = x[16384 x 1024] @ [W_proj | W_phase] + [b_proj | b_phase]
// 128x128 tile, BK=16, 256 threads, 8x8 microtile (split 4+4 for LDS bank spread)
// ---------------------------------------------------------------------------
__global__ __launch_bounds__(256) void k_gemm1(
    const float* __restrict__ X,
    const float* __restrict__ Wp,  // 1024 x 768
    const float* __restrict__ bp,  // 768
    const float* __restrict__ Wph, // 1024 x 128
    const float* __restrict__ bph, // 128
    float* __restrict__ C)         // 16384 x 896
{
    __shared__ float As[16][128];
    __shared__ float Bs[16][128];
    const int tid = threadIdx.x;
    const int tx = tid & 15, ty = tid >> 4;
    const int bx = blockIdx.x, by = blockIdx.y;
    const int r0 = by*128;
    const bool ph = (bx == 6);
    const float* W = ph ? Wph : Wp;
    const float* bias = ph ? bph : bp;
    const int ldw = ph ? 128 : 768;
    const int col0w = ph ? 0 : bx*128;  // column offset within W/bias

    float acc[8][8] = {};
    for (int k0 = 0; k0 < 1024; k0 += 16){
        #pragma unroll
        for (int i=0;i<2;i++){
            int f = tid + i*256;        // float4 id, 512 total = 2048 floats
            int m = f >> 2, kv = f & 3;
            const float4 v = *(const float4*)&X[(size_t)(r0+m)*1024 + k0 + kv*4];
            As[kv*4+0][m]=v.x; As[kv*4+1][m]=v.y; As[kv*4+2][m]=v.z; As[kv*4+3][m]=v.w;
        }
        #pragma unroll
        for (int i=0;i<2;i++){
            int f = tid + i*256;
            int kk = f >> 5, j4 = f & 31;
            const float4 v = *(const float4*)&W[(size_t)(k0+kk)*ldw + col0w + j4*4];
            *(float4*)&Bs[kk][j4*4] = v;
        }
        __syncthreads();
        #pragma unroll
        for (int kk=0;kk<16;kk++){
            float a[8], bb[8];
            *(float4*)&a[0]  = *(const float4*)&As[kk][ty*4];
            *(float4*)&a[4]  = *(const float4*)&As[kk][64+ty*4];
            *(float4*)&bb[0] = *(const float4*)&Bs[kk][tx*4];
            *(float4*)&bb[4] = *(const float4*)&Bs[kk][64+tx*4];
            #pragma unroll
            for (int i=0;i<8;i++)
                #pragma unroll
                for (int j=0;j<8;j++)
                    acc[i][j] = fmaf(a[i], bb[j], acc[i][j]);
        }
        __syncthreads();
    }
    // epilogue
    float bl[8];
    #pragma unroll
    for (int jh=0;jh<2;jh++)
        #pragma unroll
        for (int j=0;j<4;j++)
            bl[jh*4+j] = bias[col0w + jh*64 + tx*4 + j];
    #pragma unroll
    for (int ih=0; ih<2; ih++){
        #pragma unroll
        for (int i=0;i<4;i++){
            int row = r0 + ih*64 + ty*4 + i;
            #pragma unroll
            for (int jh=0;jh<2;jh++){
                int col = jh*64 + tx*4;
                float4 o;
                o.x = acc[ih*4+i][jh*4+0] + bl[jh*4+0];
                o.y = acc[ih*4+i][jh*4+1] + bl[jh*4+1];
                o.z = acc[ih*4+i][jh*4+2] + bl[jh*4+2];
                o.w = acc[ih*4+i][jh*4+3] + bl[jh*4+3];
                *(float4*)&C[(size_t)row*896 + bx*128 + col] = o;
            }
        }
    }
}

// ---------------------------------------------------------------------------
// Scan: per (b, k) linear recurrence r[t] = alpha[t]*r[t-1] + drive[t] over N=2048.
// Block handles (b, 8 k-channels); 32 threads per channel, 64-step segments,
// Hillis-Steele scan of segment aggregates in LDS. Pass 2 fuses all post-scan
// elementwise math and writes gated rho_re/rho_im + g_out.
// ---------------------------------------------------------------------------
__global__ __launch_bounds__(256) void k_scan(
    const float* __restrict__ C1,          // 16384 x 896
    const float* __restrict__ omega_base,  // 128
    const float* __restrict__ lam_p,
    float* __restrict__ RR, float* __restrict__ RI, float* __restrict__ GO)
{
    const int tid = threadIdx.x;
    const int kl = tid & 7;
    const int tn = tid >> 3;              // 0..31 segment id
    const int k  = blockIdx.x*8 + kl;     // 0..127
    const int b  = blockIdx.y;
    const float ob  = omega_base[k];
    const float lam = lam_p[0];

    __shared__ float sA[256], sR[256], sI[256];

    const int n0 = tn*64;
    float aag=1.f, br=0.f, bi=0.f;
    for (int s=0;s<64;s++){
        const int n = n0 + s;
        const float* row = C1 + (size_t)(b*2048+n)*896;
        float Ar = row[k];
        float Om = row[128+k];
        float Ph = row[256+k];
        float Ga = row[384+k];
        float alpha = sigmoidf_(Ga);
        float A = fminf(softplusf_(Ar), 3.0f);
        float omega = fminf(fmaxf(sigmoidf_(Om)*PI_F + ob, 1e-4f), PI_F-1e-4f);
        float phi = tanhf(Ph)*PI_F;
        float pos = log1pf((float)n);
        float sa, ca; sincosf(omega*pos + phi, &sa, &ca);
        float drive = (1.f-alpha)*A;
        aag *= alpha;
        br = fmaf(alpha, br, drive*ca);
        bi = fmaf(alpha, bi, drive*sa);
    }
    sA[tid]=aag; sR[tid]=br; sI[tid]=bi;
    __syncthreads();
    #pragma unroll
    for (int off=1; off<32; off<<=1){
        float na=1.f, nr=0.f, ni=0.f;
        if (tn >= off){ na=sA[tid-off*8]; nr=sR[tid-off*8]; ni=sI[tid-off*8]; }
        __syncthreads();
        float nbr = fmaf(aag, nr, br);
        float nbi = fmaf(aag, ni, bi);
        aag = aag*na; br=nbr; bi=nbi;
        sA[tid]=aag; sR[tid]=br; sI[tid]=bi;
        __syncthreads();
    }
    float rr=0.f, ri=0.f;
    if (tn > 0){ rr=sR[tid-8]; ri=sI[tid-8]; }

    for (int s=0;s<64;s++){
        const int n = n0+s;
        const float* row = C1 + (size_t)(b*2048+n)*896;
        float Ar = row[k];
        float Om = row[128+k];
        float Ph = row[256+k];
        float Ga = row[384+k];
        float Go = row[512+k];
        float Be = row[640+k];
        float pq = row[768+k];
        float alpha = sigmoidf_(Ga);
        float A = fminf(softplusf_(Ar), 3.0f);
        float omega = fminf(fmaxf(sigmoidf_(Om)*PI_F + ob, 1e-4f), PI_F-1e-4f);
        float phi = tanhf(Ph)*PI_F;
        float pos = log1pf((float)n);
        float sa, ca; sincosf(omega*pos + phi, &sa, &ca);
        float drive = (1.f-alpha)*A;
        rr = fmaf(alpha, rr, drive*ca);
        ri = fmaf(alpha, ri, drive*sa);
        float readout = rr*ca + ri*sa;
        float beta = sigmoidf_(Be);
        float r2r = rr - beta*readout*ca;
        float r2i = ri - beta*readout*sa;
        float modulus = sqrtf(r2r*r2r + r2i*r2i + 1e-8f);
        float scale = fmaxf(modulus, 1.0f);
        r2r /= scale; r2i /= scale;
        float rho_re =  r2r*ca + r2i*sa;
        float rho_im = -r2r*sa + r2i*ca;
        float rho_norm = sqrtf(rho_re*rho_re + rho_im*rho_im + 1e-6f);
        float spq, cpq; sincosf(pq, &spq, &cpq);
        float align = (rho_re*cpq + rho_im*spq)/rho_norm;
        float gate = sigmoidf_(lam*align);
        rho_re *= gate; rho_im *= gate;
        float go = sigmoidf_(Go);
        size_t idx = (size_t)(b*2048+n)*128 + k;
        RR[idx]=rho_re; RI[idx]=rho_im; GO[idx]=go;
    }
}

// ---------------------------------------------------------------------------
// Feats: (16384 x 512) = [g_out*rho_re(128) | g_out*rho_im(128) | cross_re(127) | cross_im(127) | 0 0]
// ---------------------------------------------------------------------------
__global__ __launch_bounds__(256) void k_feats(
    const float* __restrict__ RR, const float* __restrict__ RI, const float* __restrict__ GO,
    float* __restrict__ F)
{
    const int row = blockIdx.x;
    const int tid = threadIdx.x;
    __shared__ float sre[128], sim[128], sgo[128];
    if (tid < 128){
        sre[tid] = RR[(size_t)row*128+tid];
        sim[tid] = RI[(size_t)row*128+tid];
        sgo[tid] = GO[(size_t)row*128+tid];
    }
    __syncthreads();
    #pragma unroll
    for (int t=0;t<2;t++){
        int j = tid + t*256;
        float v;
        if (j < 128)       v = sgo[j]*sre[j];
        else if (j < 256)  v = sgo[j-128]*sim[j-128];
        else if (j < 383){ int kk=j-256; v = sre[kk]*sre[kk+1] + sim[kk]*sim[kk+1]; }
        else if (j < 510){ int kk=j-383; v = sim[kk]*sre[kk+1] - sre[kk]*sim[kk+1]; }
        else v = 0.f;
        F[(size_t)row*512 + j] = v;
    }
}

// ---------------------------------------------------------------------------
// GEMM2: O[16384 x 1024] = X + rs * (F[16384 x 512] @ W_res[510 x 1024])
// ---------------------------------------------------------------------------
__global__ __launch_bounds__(256) void k_gemm2(
    const float* __restrict__ F,
    const float* __restrict__ Wr,   // 510 x 1024
    const float* __restrict__ X,
    const float* __restrict__ rs_p,
    float* __restrict__ O)
{
    __shared__ float As[16][128];
    __shared__ float Bs[16][128];
    const int tid = threadIdx.x;
    const int tx = tid & 15, ty = tid >> 4;
    const int bx = blockIdx.x, by = blockIdx.y;
    const int r0 = by*128, col0 = bx*128;
    float acc[8][8] = {};
    for (int k0 = 0; k0 < 512; k0 += 16){
        #pragma unroll
        for (int i=0;i<2;i++){
            int f = tid + i*256;
            int m = f >> 2, kv = f & 3;
            const float4 v = *(const float4*)&F[(size_t)(r0+m)*512 + k0 + kv*4];
            As[kv*4+0][m]=v.x; As[kv*4+1][m]=v.y; As[kv*4+2][m]=v.z; As[kv*4+3][m]=v.w;
        }
        #pragma unroll
        for (int i=0;i<2;i++){
            int f = tid + i*256;
            int kk = f >> 5, j4 = f & 31;
            int kr = k0 + kk;
            float4 v = make_float4(0.f,0.f,0.f,0.f);
            if (kr < 510) v = *(const float4*)&Wr[(size_t)kr*1024 + col0 + j4*4];
            *(float4*)&Bs[kk][j4*4] = v;
        }
        __syncthreads();
        #pragma unroll
        for (int kk=0;kk<16;kk++){
            float a[8], bb[8];
            *(float4*)&a[0]  = *(const float4*)&As[kk][ty*4];
            *(float4*)&a[4]  = *(const float4*)&As[kk][64+ty*4];
            *(float4*)&bb[0] = *(const float4*)&Bs[kk][tx*4];
            *(float4*)&bb[4] = *(const float4*)&Bs[kk][64+tx*4];
            #pragma unroll
            for (int i=0;i<8;i++)
                #pragma unroll
                for (int j=0;j<8;j++)
                    acc[i][j] = fmaf(a[i], bb[j], acc[i][j]);
        }
        __syncthreads();
    }
    const float rs = rs_p[0];
    #pragma unroll
    for (int ih=0; ih<2; ih++){
        #pragma unroll
        for (int i=0;i<4;i++){
            int row = r0 + ih*64 + ty*4 + i;
            #pragma unroll
            for (int jh=0;jh<2;jh++){
                int col = col0 + jh*64 + tx*4;
                float4 xv = *(const float4*)&X[(size_t)row*1024 + col];
                float4 o;
                o.x = xv.x + rs*acc[ih*4+i][jh*4+0];
                o.y = xv.y + rs*acc[ih*4+i][jh*4+1];
                o.z = xv.z + rs*acc[ih*4+i][jh*4+2];
                o.w = xv.w + rs*acc[ih*4+i][jh*4+3];
                *(float4*)&O[(size_t)row*1024 + col] = o;
            }
        }
    }
}

extern "C" void kernel_launch(void* const* d_in, const int* in_sizes, int n_in,
                              void* d_out, int out_size, void* d_ws, size_t ws_size,
                              hipStream_t stream)
{
    const float* x   = (const float*)d_in[0];
    const float* Wp  = (const float*)d_in[1];
    const float* bp  = (const float*)d_in[2];
    const float* ob  = (const float*)d_in[3];
    const float* Wph = (const float*)d_in[4];
    const float* bph = (const float*)d_in[5];
    const float* Wr  = (const float*)d_in[6];
    const float* lam = (const float*)d_in[7];
    const float* rs  = (const float*)d_in[8];
    float* out = (float*)d_out;

    float* ws = (float*)d_ws;
    float* C1 = ws;                                  // 16384*896 floats
    float* RR = ws + (size_t)16384*896;              // 16384*128
    float* RI = RR + (size_t)16384*128;
    float* GO = RI + (size_t)16384*128;
    float* F  = ws;                                  // alias C1 (dead after k_scan)

    dim3 blk(256);
    hipLaunchKernelGGL(k_gemm1, dim3(7, 128),   blk, 0, stream, x, Wp, bp, Wph, bph, C1);
    hipLaunchKernelGGL(k_scan,  dim3(16, 8),    blk, 0, stream, C1, ob, lam, RR, RI, GO);
    hipLaunchKernelGGL(k_feats, dim3(16384),    blk, 0, stream, RR, RI, GO, F);
    hipLaunchKernelGGL(k_gemm2, dim3(8, 128),   blk, 0, stream, F, Wr, x, rs, out);
}

// Round 2
// 291.087 us; speedup vs baseline: 2.6881x; 2.6881x over previous
//
#include <hip/hip_runtime.h>
#include <math.h>

#define PI_F 3.14159265358979323846f
typedef unsigned short u16;
typedef __attribute__((ext_vector_type(8))) short bf16x8;
typedef __attribute__((ext_vector_type(4))) float f32x4;

__device__ __forceinline__ float sigmoidf_(float x){ return 1.0f/(1.0f+__expf(-x)); }
__device__ __forceinline__ float softplusf_(float x){ return (x>20.f)? x : log1pf(__expf(x)); }
__device__ __forceinline__ u16 f2bf(float f){
    unsigned u = __float_as_uint(f);
    return (u16)((u + 0x7FFFu + ((u>>16)&1u)) >> 16);
}
__device__ __forceinline__ void gl_lds16(const u16* g, u16* l){
    __builtin_amdgcn_global_load_lds((const __attribute__((address_space(1))) void*)g,
                                     (__attribute__((address_space(3))) void*)l, 16, 0, 0);
}

// ---------------------------------------------------------------------------
// x fp32 -> bf16 (16384x1024)
// ---------------------------------------------------------------------------
__global__ __launch_bounds__(256) void k_cvt_x(const float* __restrict__ x, u16* __restrict__ xb){
    size_t i = ((size_t)blockIdx.x*256 + threadIdx.x)*8;
    float4 v0 = *(const float4*)&x[i];
    float4 v1 = *(const float4*)&x[i+4];
    ushort4 a = make_ushort4(f2bf(v0.x),f2bf(v0.y),f2bf(v0.z),f2bf(v0.w));
    ushort4 b = make_ushort4(f2bf(v1.x),f2bf(v1.y),f2bf(v1.z),f2bf(v1.w));
    *(ushort4*)&xb[i]   = a;
    *(ushort4*)&xb[i+4] = b;
}

// ---------------------------------------------------------------------------
// Transpose + convert: W[K][Ns] fp32 (k-major) -> Wt[n][KD] bf16, zero-pad k>=K
// grid (Ns/32, KD/32), block 256 (32x8)
// ---------------------------------------------------------------------------
__global__ __launch_bounds__(256) void k_tcvt(const float* __restrict__ W, u16* __restrict__ Wt,
                                              int K, int Ns, int KD){
    __shared__ float s[32][33];
    const int tx = threadIdx.x & 31, ty = threadIdx.x >> 5;
    const int k0 = blockIdx.y*32, n0 = blockIdx.x*32;
    #pragma unroll
    for (int i=0;i<4;i++){
        int k = k0 + ty + i*8;
        s[ty+i*8][tx] = (k < K) ? W[(size_t)k*Ns + n0 + tx] : 0.f;
    }
    __syncthreads();
    #pragma unroll
    for (int i=0;i<4;i++){
        int n = n0 + ty + i*8;
        Wt[(size_t)n*KD + k0 + tx] = f2bf(s[tx][ty+i*8]);
    }
}

// ---------------------------------------------------------------------------
// GEMM1 (MFMA): C1[16384 x 896] = Xb[16384x1024] @ Wt[896x1024]^T + bias
// m97 structure: 128x128 tile, BK=32, 4 waves (2x2), 16x 16x16x32 MFMA/K-step
// ---------------------------------------------------------------------------
__global__ __launch_bounds__(256) void k_mm1(
    const u16* __restrict__ A,    // [16384][1024] bf16
    const u16* __restrict__ Bt,   // [896][1024]  bf16 (N-major)
    const float* __restrict__ bp, const float* __restrict__ bph,
    float* __restrict__ C)        // [16384][896] fp32
{
    __shared__ u16 As[128*32];
    __shared__ u16 Bs[128*32];
    const int tid = threadIdx.x;
    const int w = tid>>6, lane = tid&63;
    const int wm = w>>1, wn = w&1;
    const int r0 = blockIdx.y*128, c0 = blockIdx.x*128;

    const u16* ga[2]; const u16* gb[2]; u16 *la[2], *lb[2];
    #pragma unroll
    for (int i=0;i<2;i++){
        ga[i] = A  + (size_t)(r0 + w*32 + i*16 + (lane>>2))*1024 + (lane&3)*8;
        gb[i] = Bt + (size_t)(c0 + w*32 + i*16 + (lane>>2))*1024 + (lane&3)*8;
        la[i] = As + w*1024 + i*512;
        lb[i] = Bs + w*1024 + i*512;
    }
    const int lr = lane&15, lk = lane>>4;
    const int ao = (wm*64 + lr)*32 + lk*8;
    const int bo = (wn*64 + lr)*32 + lk*8;

    f32x4 acc[4][4] = {};
    for (int k0=0; k0<1024; k0+=32){
        gl_lds16(ga[0]+k0, la[0]); gl_lds16(ga[1]+k0, la[1]);
        gl_lds16(gb[0]+k0, lb[0]); gl_lds16(gb[1]+k0, lb[1]);
        __syncthreads();
        bf16x8 af[4], bfr[4];
        #pragma unroll
        for (int m=0;m<4;m++) af[m]  = *(const bf16x8*)&As[ao + m*512];
        #pragma unroll
        for (int n=0;n<4;n++) bfr[n] = *(const bf16x8*)&Bs[bo + n*512];
        #pragma unroll
        for (int m=0;m<4;m++)
            #pragma unroll
            for (int n=0;n<4;n++)
                acc[m][n] = __builtin_amdgcn_mfma_f32_16x16x32_bf16(af[m], bfr[n], acc[m][n], 0,0,0);
        __syncthreads();
    }
    #pragma unroll
    for (int n=0;n<4;n++){
        int col = c0 + wn*64 + n*16 + lr;
        float bl = (col < 768) ? bp[col] : bph[col-768];
        #pragma unroll
        for (int m=0;m<4;m++){
            int row = r0 + wm*64 + m*16 + lk*4;
            #pragma unroll
            for (int r=0;r<4;r++)
                C[(size_t)(row+r)*896 + col] = acc[m][n][r] + bl;
        }
    }
}

// ---------------------------------------------------------------------------
// GEMM2 (MFMA): O[16384x1024] = X + rs*( F[16384x512] @ Wrt[1024x512]^T )
// ---------------------------------------------------------------------------
__global__ __launch_bounds__(256) void k_mm2(
    const u16* __restrict__ A,    // F [16384][512] bf16 (cols 510,511 zero)
    const u16* __restrict__ Bt,   // Wrt [1024][512] bf16 (k>=510 zero)
    const float* __restrict__ X,
    const float* __restrict__ rs_p,
    float* __restrict__ O)
{
    __shared__ u16 As[128*32];
    __shared__ u16 Bs[128*32];
    const int tid = threadIdx.x;
    const int w = tid>>6, lane = tid&63;
    const int wm = w>>1, wn = w&1;
    const int r0 = blockIdx.y*128, c0 = blockIdx.x*128;

    const u16* ga[2]; const u16* gb[2]; u16 *la[2], *lb[2];
    #pragma unroll
    for (int i=0;i<2;i++){
        ga[i] = A  + (size_t)(r0 + w*32 + i*16 + (lane>>2))*512 + (lane&3)*8;
        gb[i] = Bt + (size_t)(c0 + w*32 + i*16 + (lane>>2))*512 + (lane&3)*8;
        la[i] = As + w*1024 + i*512;
        lb[i] = Bs + w*1024 + i*512;
    }
    const int lr = lane&15, lk = lane>>4;
    const int ao = (wm*64 + lr)*32 + lk*8;
    const int bo = (wn*64 + lr)*32 + lk*8;

    f32x4 acc[4][4] = {};
    for (int k0=0; k0<512; k0+=32){
        gl_lds16(ga[0]+k0, la[0]); gl_lds16(ga[1]+k0, la[1]);
        gl_lds16(gb[0]+k0, lb[0]); gl_lds16(gb[1]+k0, lb[1]);
        __syncthreads();
        bf16x8 af[4], bfr[4];
        #pragma unroll
        for (int m=0;m<4;m++) af[m]  = *(const bf16x8*)&As[ao + m*512];
        #pragma unroll
        for (int n=0;n<4;n++) bfr[n] = *(const bf16x8*)&Bs[bo + n*512];
        #pragma unroll
        for (int m=0;m<4;m++)
            #pragma unroll
            for (int n=0;n<4;n++)
                acc[m][n] = __builtin_amdgcn_mfma_f32_16x16x32_bf16(af[m], bfr[n], acc[m][n], 0,0,0);
        __syncthreads();
    }
    const float rs = rs_p[0];
    #pragma unroll
    for (int n=0;n<4;n++){
        int col = c0 + wn*64 + n*16 + lr;
        #pragma unroll
        for (int m=0;m<4;m++){
            int row = r0 + wm*64 + m*16 + lk*4;
            #pragma unroll
            for (int r=0;r<4;r++){
                size_t idx = (size_t)(row+r)*1024 + col;
                O[idx] = X[idx] + rs*acc[m][n][r];
            }
        }
    }
}

// ---------------------------------------------------------------------------
// Scan (unchanged from R1): per (b,k) recurrence over N=2048, Hillis-Steele
// over 32 segment aggregates, fused post-scan elementwise.
// ---------------------------------------------------------------------------
__global__ __launch_bounds__(256) void k_scan(
    const float* __restrict__ C1,          // 16384 x 896
    const float* __restrict__ omega_base,  // 128
    const float* __restrict__ lam_p,
    float* __restrict__ RR, float* __restrict__ RI, float* __restrict__ GO)
{
    const int tid = threadIdx.x;
    const int kl = tid & 7;
    const int tn = tid >> 3;
    const int k  = blockIdx.x*8 + kl;
    const int b  = blockIdx.y;
    const float ob  = omega_base[k];
    const float lam = lam_p[0];

    __shared__ float sA[256], sR[256], sI[256];

    const int n0 = tn*64;
    float aag=1.f, br=0.f, bi=0.f;
    for (int s=0;s<64;s++){
        const int n = n0 + s;
        const float* row = C1 + (size_t)(b*2048+n)*896;
        float Ar = row[k];
        float Om = row[128+k];
        float Ph = row[256+k];
        float Ga = row[384+k];
        float alpha = sigmoidf_(Ga);
        float A = fminf(softplusf_(Ar), 3.0f);
        float omega = fminf(fmaxf(sigmoidf_(Om)*PI_F + ob, 1e-4f), PI_F-1e-4f);
        float phi = tanhf(Ph)*PI_F;
        float pos = log1pf((float)n);
        float sa, ca; sincosf(omega*pos + phi, &sa, &ca);
        float drive = (1.f-alpha)*A;
        aag *= alpha;
        br = fmaf(alpha, br, drive*ca);
        bi = fmaf(alpha, bi, drive*sa);
    }
    sA[tid]=aag; sR[tid]=br; sI[tid]=bi;
    __syncthreads();
    #pragma unroll
    for (int off=1; off<32; off<<=1){
        float na=1.f, nr=0.f, ni=0.f;
        if (tn >= off){ na=sA[tid-off*8]; nr=sR[tid-off*8]; ni=sI[tid-off*8]; }
        __syncthreads();
        float nbr = fmaf(aag, nr, br);
        float nbi = fmaf(aag, ni, bi);
        aag = aag*na; br=nbr; bi=nbi;
        sA[tid]=aag; sR[tid]=br; sI[tid]=bi;
        __syncthreads();
    }
    float rr=0.f, ri=0.f;
    if (tn > 0){ rr=sR[tid-8]; ri=sI[tid-8]; }

    for (int s=0;s<64;s++){
        const int n = n0+s;
        const float* row = C1 + (size_t)(b*2048+n)*896;
        float Ar = row[k];
        float Om = row[128+k];
        float Ph = row[256+k];
        float Ga = row[384+k];
        float Go = row[512+k];
        float Be = row[640+k];
        float pq = row[768+k];
        float alpha = sigmoidf_(Ga);
        float A = fminf(softplusf_(Ar), 3.0f);
        float omega = fminf(fmaxf(sigmoidf_(Om)*PI_F + ob, 1e-4f), PI_F-1e-4f);
        float phi = tanhf(Ph)*PI_F;
        float pos = log1pf((float)n);
        float sa, ca; sincosf(omega*pos + phi, &sa, &ca);
        float drive = (1.f-alpha)*A;
        rr = fmaf(alpha, rr, drive*ca);
        ri = fmaf(alpha, ri, drive*sa);
        float readout = rr*ca + ri*sa;
        float beta = sigmoidf_(Be);
        float r2r = rr - beta*readout*ca;
        float r2i = ri - beta*readout*sa;
        float modulus = sqrtf(r2r*r2r + r2i*r2i + 1e-8f);
        float scale = fmaxf(modulus, 1.0f);
        r2r /= scale; r2i /= scale;
        float rho_re =  r2r*ca + r2i*sa;
        float rho_im = -r2r*sa + r2i*ca;
        float rho_norm = sqrtf(rho_re*rho_re + rho_im*rho_im + 1e-6f);
        float spq, cpq; sincosf(pq, &spq, &cpq);
        float align = (rho_re*cpq + rho_im*spq)/rho_norm;
        float gate = sigmoidf_(lam*align);
        rho_re *= gate; rho_im *= gate;
        float go = sigmoidf_(Go);
        size_t idx = (size_t)(b*2048+n)*128 + k;
        RR[idx]=rho_re; RI[idx]=rho_im; GO[idx]=go;
    }
}

// ---------------------------------------------------------------------------
// Feats -> bf16: F[16384 x 512] = [go*rr(128) | go*ri(128) | cross_re(127) | cross_im(127) | 0 0]
// ---------------------------------------------------------------------------
__global__ __launch_bounds__(256) void k_feats(
    const float* __restrict__ RR, const float* __restrict__ RI, const float* __restrict__ GO,
    u16* __restrict__ F)
{
    const int row = blockIdx.x;
    const int tid = threadIdx.x;
    __shared__ float sre[128], sim[128], sgo[128];
    if (tid < 128){
        sre[tid] = RR[(size_t)row*128+tid];
        sim[tid] = RI[(size_t)row*128+tid];
        sgo[tid] = GO[(size_t)row*128+tid];
    }
    __syncthreads();
    #pragma unroll
    for (int t=0;t<2;t++){
        int j = tid + t*256;
        float v;
        if (j < 128)       v = sgo[j]*sre[j];
        else if (j < 256)  v = sgo[j-128]*sim[j-128];
        else if (j < 383){ int kk=j-256; v = sre[kk]*sre[kk+1] + sim[kk]*sim[kk+1]; }
        else if (j < 510){ int kk=j-383; v = sim[kk]*sre[kk+1] - sre[kk]*sim[kk+1]; }
        else v = 0.f;
        F[(size_t)row*512 + j] = f2bf(v);
    }
}

extern "C" void kernel_launch(void* const* d_in, const int* in_sizes, int n_in,
                              void* d_out, int out_size, void* d_ws, size_t ws_size,
                              hipStream_t stream)
{
    const float* x   = (const float*)d_in[0];
    const float* Wp  = (const float*)d_in[1];
    const float* bp  = (const float*)d_in[2];
    const float* ob  = (const float*)d_in[3];
    const float* Wph = (const float*)d_in[4];
    const float* bph = (const float*)d_in[5];
    const float* Wr  = (const float*)d_in[6];
    const float* lam = (const float*)d_in[7];
    const float* rs  = (const float*)d_in[8];
    float* out = (float*)d_out;

    char* ws = (char*)d_ws;
    // layout (bytes):
    //   [0, 58720256)               C1 fp32 16384x896   (later aliased by F bf16 16384x512 = 16.8MB)
    //   [58720256, +33554432)       Xb bf16 16384x1024  (later aliased by RR/RI/GO fp32 3x 8.39MB)
    //   [92274688, +1835008)        Wt bf16 896x1024
    //   [94109696, +1048576)        Wrt bf16 1024x512
    float* C1  = (float*)(ws + 0);
    u16*   Xb  = (u16*)  (ws + 58720256);
    float* RR  = (float*)(ws + 58720256);
    float* RI  = (float*)(ws + 58720256 + 8388608);
    float* GO  = (float*)(ws + 58720256 + 16777216);
    u16*   Wt  = (u16*)  (ws + 92274688);
    u16*   Wrt = (u16*)  (ws + 94109696);
    u16*   F   = (u16*)  (ws + 0);

    dim3 blk(256);
    hipLaunchKernelGGL(k_cvt_x, dim3(8192),  blk, 0, stream, x, Xb);
    hipLaunchKernelGGL(k_tcvt,  dim3(24,32), blk, 0, stream, Wp,  Wt,            1024, 768,  1024);
    hipLaunchKernelGGL(k_tcvt,  dim3(4,32),  blk, 0, stream, Wph, Wt + 768*1024, 1024, 128,  1024);
    hipLaunchKernelGGL(k_tcvt,  dim3(32,16), blk, 0, stream, Wr,  Wrt,           510,  1024, 512);
    hipLaunchKernelGGL(k_mm1,   dim3(7,128), blk, 0, stream, Xb, Wt, bp, bph, C1);
    hipLaunchKernelGGL(k_scan,  dim3(16,8),  blk, 0, stream, C1, ob, lam, RR, RI, GO);
    hipLaunchKernelGGL(k_feats, dim3(16384), blk, 0, stream, RR, RI, GO, F);
    hipLaunchKernelGGL(k_mm2,   dim3(8,128), blk, 0, stream, F, Wrt, x, rs, out);
}

// Round 4
// 204.666 us; speedup vs baseline: 3.8231x; 1.4223x over previous
//
#include <hip/hip_runtime.h>
#include <math.h>

#define PI_F 3.14159265358979323846f
#define SEG 128
#define SLEN 16
typedef unsigned short u16;
typedef __attribute__((ext_vector_type(8))) short bf16x8;
typedef __attribute__((ext_vector_type(4))) float f32x4;

__device__ __forceinline__ float sigmoidf_(float x){ return 1.0f/(1.0f+__expf(-x)); }
__device__ __forceinline__ float softplusf_(float x){ return (x>20.f)? x : log1pf(__expf(x)); }
__device__ __forceinline__ u16 f2bf(float f){
    unsigned u = __float_as_uint(f);
    return (u16)((u + 0x7FFFu + ((u>>16)&1u)) >> 16);
}
__device__ __forceinline__ void gl_lds16(const u16* g, u16* l){
    __builtin_amdgcn_global_load_lds((const __attribute__((address_space(1))) void*)g,
                                     (__attribute__((address_space(3))) void*)l, 16, 0, 0);
}

// ---------------------------------------------------------------------------
// x fp32 -> bf16 (16384x1024)
// ---------------------------------------------------------------------------
__global__ __launch_bounds__(256) void k_cvt_x(const float* __restrict__ x, u16* __restrict__ xb){
    size_t i = ((size_t)blockIdx.x*256 + threadIdx.x)*8;
    float4 v0 = *(const float4*)&x[i];
    float4 v1 = *(const float4*)&x[i+4];
    ushort4 a = make_ushort4(f2bf(v0.x),f2bf(v0.y),f2bf(v0.z),f2bf(v0.w));
    ushort4 b = make_ushort4(f2bf(v1.x),f2bf(v1.y),f2bf(v1.z),f2bf(v1.w));
    *(ushort4*)&xb[i]   = a;
    *(ushort4*)&xb[i+4] = b;
}

// ---------------------------------------------------------------------------
// Transpose + convert: W[K][Ns] fp32 (k-major) -> Wt[n][KD] bf16, zero-pad k>=K
// ---------------------------------------------------------------------------
__global__ __launch_bounds__(256) void k_tcvt(const float* __restrict__ W, u16* __restrict__ Wt,
                                              int K, int Ns, int KD){
    __shared__ float s[32][33];
    const int tx = threadIdx.x & 31, ty = threadIdx.x >> 5;
    const int k0 = blockIdx.y*32, n0 = blockIdx.x*32;
    #pragma unroll
    for (int i=0;i<4;i++){
        int k = k0 + ty + i*8;
        s[ty+i*8][tx] = (k < K) ? W[(size_t)k*Ns + n0 + tx] : 0.f;
    }
    __syncthreads();
    #pragma unroll
    for (int i=0;i<4;i++){
        int n = n0 + ty + i*8;
        Wt[(size_t)n*KD + k0 + tx] = f2bf(s[tx][ty+i*8]);
    }
}

// ---------------------------------------------------------------------------
// GEMM1 (MFMA): C1[16384 x 896] = Xb[16384x1024] @ Wt[896x1024]^T + bias
// ---------------------------------------------------------------------------
__global__ __launch_bounds__(256) void k_mm1(
    const u16* __restrict__ A,
    const u16* __restrict__ Bt,
    const float* __restrict__ bp, const float* __restrict__ bph,
    float* __restrict__ C)
{
    __shared__ u16 As[128*32];
    __shared__ u16 Bs[128*32];
    const int tid = threadIdx.x;
    const int w = tid>>6, lane = tid&63;
    const int wm = w>>1, wn = w&1;
    const int r0 = blockIdx.y*128, c0 = blockIdx.x*128;

    const u16* ga[2]; const u16* gb[2]; u16 *la[2], *lb[2];
    #pragma unroll
    for (int i=0;i<2;i++){
        ga[i] = A  + (size_t)(r0 + w*32 + i*16 + (lane>>2))*1024 + (lane&3)*8;
        gb[i] = Bt + (size_t)(c0 + w*32 + i*16 + (lane>>2))*1024 + (lane&3)*8;
        la[i] = As + w*1024 + i*512;
        lb[i] = Bs + w*1024 + i*512;
    }
    const int lr = lane&15, lk = lane>>4;
    const int ao = (wm*64 + lr)*32 + lk*8;
    const int bo = (wn*64 + lr)*32 + lk*8;

    f32x4 acc[4][4] = {};
    for (int k0=0; k0<1024; k0+=32){
        gl_lds16(ga[0]+k0, la[0]); gl_lds16(ga[1]+k0, la[1]);
        gl_lds16(gb[0]+k0, lb[0]); gl_lds16(gb[1]+k0, lb[1]);
        __syncthreads();
        bf16x8 af[4], bfr[4];
        #pragma unroll
        for (int m=0;m<4;m++) af[m]  = *(const bf16x8*)&As[ao + m*512];
        #pragma unroll
        for (int n=0;n<4;n++) bfr[n] = *(const bf16x8*)&Bs[bo + n*512];
        #pragma unroll
        for (int m=0;m<4;m++)
            #pragma unroll
            for (int n=0;n<4;n++)
                acc[m][n] = __builtin_amdgcn_mfma_f32_16x16x32_bf16(af[m], bfr[n], acc[m][n], 0,0,0);
        __syncthreads();
    }
    #pragma unroll
    for (int n=0;n<4;n++){
        int col = c0 + wn*64 + n*16 + lr;
        float bl = (col < 768) ? bp[col] : bph[col-768];
        #pragma unroll
        for (int m=0;m<4;m++){
            int row = r0 + wm*64 + m*16 + lk*4;
            #pragma unroll
            for (int r=0;r<4;r++)
                C[(size_t)(row+r)*896 + col] = acc[m][n][r] + bl;
        }
    }
}

// ---------------------------------------------------------------------------
// GEMM2 (MFMA): O[16384x1024] = X + rs*( F[16384x512] @ Wrt[1024x512]^T )
// ---------------------------------------------------------------------------
__global__ __launch_bounds__(256) void k_mm2(
    const u16* __restrict__ A,
    const u16* __restrict__ Bt,
    const float* __restrict__ X,
    const float* __restrict__ rs_p,
    float* __restrict__ O)
{
    __shared__ u16 As[128*32];
    __shared__ u16 Bs[128*32];
    const int tid = threadIdx.x;
    const int w = tid>>6, lane = tid&63;
    const int wm = w>>1, wn = w&1;
    const int r0 = blockIdx.y*128, c0 = blockIdx.x*128;

    const u16* ga[2]; const u16* gb[2]; u16 *la[2], *lb[2];
    #pragma unroll
    for (int i=0;i<2;i++){
        ga[i] = A  + (size_t)(r0 + w*32 + i*16 + (lane>>2))*512 + (lane&3)*8;
        gb[i] = Bt + (size_t)(c0 + w*32 + i*16 + (lane>>2))*512 + (lane&3)*8;
        la[i] = As + w*1024 + i*512;
        lb[i] = Bs + w*1024 + i*512;
    }
    const int lr = lane&15, lk = lane>>4;
    const int ao = (wm*64 + lr)*32 + lk*8;
    const int bo = (wn*64 + lr)*32 + lk*8;

    f32x4 acc[4][4] = {};
    for (int k0=0; k0<512; k0+=32){
        gl_lds16(ga[0]+k0, la[0]); gl_lds16(ga[1]+k0, la[1]);
        gl_lds16(gb[0]+k0, lb[0]); gl_lds16(gb[1]+k0, lb[1]);
        __syncthreads();
        bf16x8 af[4], bfr[4];
        #pragma unroll
        for (int m=0;m<4;m++) af[m]  = *(const bf16x8*)&As[ao + m*512];
        #pragma unroll
        for (int n=0;n<4;n++) bfr[n] = *(const bf16x8*)&Bs[bo + n*512];
        #pragma unroll
        for (int m=0;m<4;m++)
            #pragma unroll
            for (int n=0;n<4;n++)
                acc[m][n] = __builtin_amdgcn_mfma_f32_16x16x32_bf16(af[m], bfr[n], acc[m][n], 0,0,0);
        __syncthreads();
    }
    const float rs = rs_p[0];
    #pragma unroll
    for (int n=0;n<4;n++){
        int col = c0 + wn*64 + n*16 + lr;
        #pragma unroll
        for (int m=0;m<4;m++){
            int row = r0 + wm*64 + m*16 + lk*4;
            #pragma unroll
            for (int r=0;r<4;r++){
                size_t idx = (size_t)(row+r)*1024 + col;
                O[idx] = X[idx] + rs*acc[m][n][r];
            }
        }
    }
}

// ---------------------------------------------------------------------------
// S1: per-segment aggregates. grid (SEG, B), block 128 (thread = k).
// ---------------------------------------------------------------------------
__global__ __launch_bounds__(128) void k_s1(
    const float* __restrict__ C1,
    const float* __restrict__ omega_base,
    float* __restrict__ Ag, float* __restrict__ Br, float* __restrict__ Bi)
{
    const int k = threadIdx.x;
    const int seg = blockIdx.x, b = blockIdx.y;
    const float ob = omega_base[k];
    const int n0 = seg*SLEN;
    float aag = 1.f, br = 0.f, bi = 0.f;
    #pragma unroll 4
    for (int s=0; s<SLEN; s++){
        const int n = n0 + s;
        const float* row = C1 + (size_t)(b*2048+n)*896;
        float Ar = row[k];
        float Om = row[128+k];
        float Ph = row[256+k];
        float Ga = row[384+k];
        float alpha = sigmoidf_(Ga);
        float A = fminf(softplusf_(Ar), 3.0f);
        float omega = fminf(fmaxf(sigmoidf_(Om)*PI_F + ob, 1e-4f), PI_F-1e-4f);
        float phi = tanhf(Ph)*PI_F;
        float pos = log1pf((float)n);
        float sa, ca; sincosf(omega*pos + phi, &sa, &ca);
        float drive = (1.f-alpha)*A;
        aag *= alpha;
        br = fmaf(alpha, br, drive*ca);
        bi = fmaf(alpha, bi, drive*sa);
    }
    const size_t o = (size_t)(b*SEG + seg)*128 + k;
    Ag[o] = aag; Br[o] = br; Bi[o] = bi;
}

// ---------------------------------------------------------------------------
// S2: serial scan over SEG aggregates per (b,k) channel; writes entry prefix.
// ---------------------------------------------------------------------------
__global__ __launch_bounds__(256) void k_s2(
    const float* __restrict__ Ag, const float* __restrict__ Br, const float* __restrict__ Bi,
    float* __restrict__ Pr, float* __restrict__ Pi)
{
    const int gid = blockIdx.x*256 + threadIdx.x;   // 0..1023
    const int b = gid >> 7, k = gid & 127;
    float pr = 0.f, pi = 0.f;
    #pragma unroll 8
    for (int seg=0; seg<SEG; seg++){
        const size_t o = (size_t)(b*SEG + seg)*128 + k;
        float a = Ag[o], r = Br[o], i = Bi[o];
        Pr[o] = pr; Pi[o] = pi;
        pr = fmaf(a, pr, r);
        pi = fmaf(a, pi, i);
    }
}

// ---------------------------------------------------------------------------
// S3: apply prefixes, full post-scan elementwise, neighbor-k cross via LDS,
// write feats F bf16 [16384 x 512] directly.
// ---------------------------------------------------------------------------
__global__ __launch_bounds__(128) void k_s3(
    const float* __restrict__ C1,
    const float* __restrict__ omega_base,
    const float* __restrict__ lam_p,
    const float* __restrict__ Pr, const float* __restrict__ Pi,
    u16* __restrict__ F)
{
    const int k = threadIdx.x;
    const int seg = blockIdx.x, b = blockIdx.y;
    const float ob = omega_base[k];
    const float lam = lam_p[0];
    __shared__ float sre[2][129], sim[2][129];

    const size_t po = (size_t)(b*SEG + seg)*128 + k;
    float rr = Pr[po], ri = Pi[po];
    const int n0 = seg*SLEN;

    #pragma unroll 2
    for (int s=0; s<SLEN; s++){
        const int n = n0 + s;
        const float* row = C1 + (size_t)(b*2048+n)*896;
        float Ar = row[k];
        float Om = row[128+k];
        float Ph = row[256+k];
        float Ga = row[384+k];
        float Go = row[512+k];
        float Be = row[640+k];
        float pq = row[768+k];
        float alpha = sigmoidf_(Ga);
        float A = fminf(softplusf_(Ar), 3.0f);
        float omega = fminf(fmaxf(sigmoidf_(Om)*PI_F + ob, 1e-4f), PI_F-1e-4f);
        float phi = tanhf(Ph)*PI_F;
        float pos = log1pf((float)n);
        float sa, ca; sincosf(omega*pos + phi, &sa, &ca);
        float drive = (1.f-alpha)*A;
        rr = fmaf(alpha, rr, drive*ca);
        ri = fmaf(alpha, ri, drive*sa);
        float readout = rr*ca + ri*sa;
        float beta = sigmoidf_(Be);
        float r2r = rr - beta*readout*ca;
        float r2i = ri - beta*readout*sa;
        float modulus = sqrtf(r2r*r2r + r2i*r2i + 1e-8f);
        float scale = fmaxf(modulus, 1.0f);
        r2r /= scale; r2i /= scale;
        float rho_re =  r2r*ca + r2i*sa;
        float rho_im = -r2r*sa + r2i*ca;
        float rho_norm = sqrtf(rho_re*rho_re + rho_im*rho_im + 1e-6f);
        float spq, cpq; sincosf(pq, &spq, &cpq);
        float align = (rho_re*cpq + rho_im*spq)/rho_norm;
        float gate = sigmoidf_(lam*align);
        rho_re *= gate; rho_im *= gate;
        float go = sigmoidf_(Go);

        const int buf = s & 1;
        sre[buf][k] = rho_re; sim[buf][k] = rho_im;
        __syncthreads();

        u16* frow = F + (size_t)(b*2048+n)*512;
        frow[k]       = f2bf(go*rho_re);
        frow[128 + k] = f2bf(go*rho_im);
        if (k < 127){
            float nre = sre[buf][k+1], nim = sim[buf][k+1];
            frow[256 + k] = f2bf(rho_re*nre + rho_im*nim);
            frow[383 + k] = f2bf(rho_im*nre - rho_re*nim);
        } else {
            frow[510] = 0; frow[511] = 0;
        }
    }
}

extern "C" void kernel_launch(void* const* d_in, const int* in_sizes, int n_in,
                              void* d_out, int out_size, void* d_ws, size_t ws_size,
                              hipStream_t stream)
{
    const float* x   = (const float*)d_in[0];
    const float* Wp  = (const float*)d_in[1];
    const float* bp  = (const float*)d_in[2];
    const float* ob  = (const float*)d_in[3];
    const float* Wph = (const float*)d_in[4];
    const float* bph = (const float*)d_in[5];
    const float* Wr  = (const float*)d_in[6];
    const float* lam = (const float*)d_in[7];
    const float* rs  = (const float*)d_in[8];
    float* out = (float*)d_out;

    char* ws = (char*)d_ws;
    // layout (bytes):
    //   [0, 58720256)            C1 fp32 16384x896
    //   [58720256, +33554432)    Xb bf16 (dead after mm1) -> aliased by:
    //        +0        Ag 512KB, +524288 Br, +1048576 Bi, +1572864 Pr, +2097152 Pi
    //        +2621440  F bf16 16384x512 (16.78MB)
    //   [92274688, +1835008)     Wt bf16 896x1024
    //   [94109696, +1048576)     Wrt bf16 1024x512
    float* C1  = (float*)(ws + 0);
    u16*   Xb  = (u16*)  (ws + 58720256);
    float* Ag  = (float*)(ws + 58720256);
    float* Brr = (float*)(ws + 58720256 +  524288);
    float* Bii = (float*)(ws + 58720256 + 1048576);
    float* Pr  = (float*)(ws + 58720256 + 1572864);
    float* Pi  = (float*)(ws + 58720256 + 2097152);
    u16*   F   = (u16*)  (ws + 58720256 + 2621440);
    u16*   Wt  = (u16*)  (ws + 92274688);
    u16*   Wrt = (u16*)  (ws + 94109696);

    dim3 blk(256);
    hipLaunchKernelGGL(k_cvt_x, dim3(8192),   blk, 0, stream, x, Xb);
    hipLaunchKernelGGL(k_tcvt,  dim3(24,32),  blk, 0, stream, Wp,  Wt,            1024, 768,  1024);
    hipLaunchKernelGGL(k_tcvt,  dim3(4,32),   blk, 0, stream, Wph, Wt + 768*1024, 1024, 128,  1024);
    hipLaunchKernelGGL(k_tcvt,  dim3(32,16),  blk, 0, stream, Wr,  Wrt,           510,  1024, 512);
    hipLaunchKernelGGL(k_mm1,   dim3(7,128),  blk, 0, stream, Xb, Wt, bp, bph, C1);
    hipLaunchKernelGGL(k_s1,    dim3(SEG,8),  dim3(128), 0, stream, C1, ob, Ag, Brr, Bii);
    hipLaunchKernelGGL(k_s2,    dim3(4),      blk, 0, stream, Ag, Brr, Bii, Pr, Pi);
    hipLaunchKernelGGL(k_s3,    dim3(SEG,8),  dim3(128), 0, stream, C1, ob, lam, Pr, Pi, F);
    hipLaunchKernelGGL(k_mm2,   dim3(8,128),  blk, 0, stream, F, Wrt, x, rs, out);
}

// Round 5
// 152.653 us; speedup vs baseline: 5.1258x; 1.3407x over previous
//
#include <hip/hip_runtime.h>
#include <math.h>

#define PI_F 3.14159265358979323846f
#define SEG 128
#define SLEN 16
typedef unsigned short u16;
typedef __attribute__((ext_vector_type(8))) short bf16x8;
typedef __attribute__((ext_vector_type(4))) float f32x4;

__device__ __forceinline__ float sigmoidf_(float x){ return __fdividef(1.0f, 1.0f+__expf(-x)); }
__device__ __forceinline__ float softplusf_(float x){
    return fmaxf(x, 0.f) + __logf(1.f + __expf(-fabsf(x)));
}
__device__ __forceinline__ float tanhpi_(float x){   // tanh(x)*PI
    float t = __expf(-2.f*fabsf(x));
    float th = __fdividef(1.f - t, 1.f + t);
    return copysignf(th, x)*PI_F;
}
__device__ __forceinline__ void fsincos(float a, float* s, float* c){
    float r = a * 0.15915494309189535f;   // a / 2pi
    r = r - floorf(r);                    // [0,1) revolutions
#if __has_builtin(__builtin_amdgcn_sinf)
    *s = __builtin_amdgcn_sinf(r);        // sin(2pi*r)
    *c = __builtin_amdgcn_cosf(r);
#else
    float t = r * 6.283185307179586f;
    *s = __sinf(t); *c = __cosf(t);
#endif
}
__device__ __forceinline__ u16 f2bf(float f){
    unsigned u = __float_as_uint(f);
    return (u16)((u + 0x7FFFu + ((u>>16)&1u)) >> 16);
}
__device__ __forceinline__ float b2f(u16 v){
    return __uint_as_float(((unsigned)v)<<16);
}
__device__ __forceinline__ void gl_lds16(const u16* g, u16* l){
    __builtin_amdgcn_global_load_lds((const __attribute__((address_space(1))) void*)g,
                                     (__attribute__((address_space(3))) void*)l, 16, 0, 0);
}

// ---------------------------------------------------------------------------
// x fp32 -> bf16 (16384x1024)
// ---------------------------------------------------------------------------
__global__ __launch_bounds__(256) void k_cvt_x(const float* __restrict__ x, u16* __restrict__ xb){
    size_t i = ((size_t)blockIdx.x*256 + threadIdx.x)*8;
    float4 v0 = *(const float4*)&x[i];
    float4 v1 = *(const float4*)&x[i+4];
    ushort4 a = make_ushort4(f2bf(v0.x),f2bf(v0.y),f2bf(v0.z),f2bf(v0.w));
    ushort4 b = make_ushort4(f2bf(v1.x),f2bf(v1.y),f2bf(v1.z),f2bf(v1.w));
    *(ushort4*)&xb[i]   = a;
    *(ushort4*)&xb[i+4] = b;
}

// ---------------------------------------------------------------------------
// Transpose + convert: W[K][Ns] fp32 (k-major) -> Wt[n][KD] bf16, zero-pad k>=K
// ---------------------------------------------------------------------------
__global__ __launch_bounds__(256) void k_tcvt(const float* __restrict__ W, u16* __restrict__ Wt,
                                              int K, int Ns, int KD){
    __shared__ float s[32][33];
    const int tx = threadIdx.x & 31, ty = threadIdx.x >> 5;
    const int k0 = blockIdx.y*32, n0 = blockIdx.x*32;
    #pragma unroll
    for (int i=0;i<4;i++){
        int k = k0 + ty + i*8;
        s[ty+i*8][tx] = (k < K) ? W[(size_t)k*Ns + n0 + tx] : 0.f;
    }
    __syncthreads();
    #pragma unroll
    for (int i=0;i<4;i++){
        int n = n0 + ty + i*8;
        Wt[(size_t)n*KD + k0 + tx] = f2bf(s[tx][ty+i*8]);
    }
}

// ---------------------------------------------------------------------------
// GEMM1 (MFMA): C1[16384 x 896] bf16 = Xb @ Wt^T + bias
// m97 structure, XCD-aware block swizzle (896 blocks = 8 XCD x 112).
// ---------------------------------------------------------------------------
__global__ __launch_bounds__(256) void k_mm1(
    const u16* __restrict__ A,
    const u16* __restrict__ Bt,
    const float* __restrict__ bp, const float* __restrict__ bph,
    u16* __restrict__ C)
{
    const int bid = blockIdx.x;
    const int swz = (bid & 7)*112 + (bid >> 3);   // XCD j owns [j*112,(j+1)*112)
    const int by = swz / 7, bx = swz - by*7;      // 7 consecutive swz share A-panel

    __shared__ u16 As[128*32];
    __shared__ u16 Bs[128*32];
    const int tid = threadIdx.x;
    const int w = tid>>6, lane = tid&63;
    const int wm = w>>1, wn = w&1;
    const int r0 = by*128, c0 = bx*128;

    const u16* ga[2]; const u16* gb[2]; u16 *la[2], *lb[2];
    #pragma unroll
    for (int i=0;i<2;i++){
        ga[i] = A  + (size_t)(r0 + w*32 + i*16 + (lane>>2))*1024 + (lane&3)*8;
        gb[i] = Bt + (size_t)(c0 + w*32 + i*16 + (lane>>2))*1024 + (lane&3)*8;
        la[i] = As + w*1024 + i*512;
        lb[i] = Bs + w*1024 + i*512;
    }
    const int lr = lane&15, lk = lane>>4;
    const int ao = (wm*64 + lr)*32 + lk*8;
    const int bo = (wn*64 + lr)*32 + lk*8;

    f32x4 acc[4][4] = {};
    for (int k0=0; k0<1024; k0+=32){
        gl_lds16(ga[0]+k0, la[0]); gl_lds16(ga[1]+k0, la[1]);
        gl_lds16(gb[0]+k0, lb[0]); gl_lds16(gb[1]+k0, lb[1]);
        __syncthreads();
        bf16x8 af[4], bfr[4];
        #pragma unroll
        for (int m=0;m<4;m++) af[m]  = *(const bf16x8*)&As[ao + m*512];
        #pragma unroll
        for (int n=0;n<4;n++) bfr[n] = *(const bf16x8*)&Bs[bo + n*512];
        #pragma unroll
        for (int m=0;m<4;m++)
            #pragma unroll
            for (int n=0;n<4;n++)
                acc[m][n] = __builtin_amdgcn_mfma_f32_16x16x32_bf16(af[m], bfr[n], acc[m][n], 0,0,0);
        __syncthreads();
    }
    #pragma unroll
    for (int n=0;n<4;n++){
        int col = c0 + wn*64 + n*16 + lr;
        float bl = (col < 768) ? bp[col] : bph[col-768];
        #pragma unroll
        for (int m=0;m<4;m++){
            int row = r0 + wm*64 + m*16 + lk*4;
            #pragma unroll
            for (int r=0;r<4;r++)
                C[(size_t)(row+r)*896 + col] = f2bf(acc[m][n][r] + bl);
        }
    }
}

// ---------------------------------------------------------------------------
// GEMM2 (MFMA): O[16384x1024] = X + rs*( F @ Wrt^T ), XCD swizzle (1024 blocks)
// ---------------------------------------------------------------------------
__global__ __launch_bounds__(256) void k_mm2(
    const u16* __restrict__ A,
    const u16* __restrict__ Bt,
    const float* __restrict__ X,
    const float* __restrict__ rs_p,
    float* __restrict__ O)
{
    const int bid = blockIdx.x;
    const int swz = (bid & 7)*128 + (bid >> 3);
    const int by = swz >> 3, bx = swz & 7;        // 8 consecutive swz share F-panel

    __shared__ u16 As[128*32];
    __shared__ u16 Bs[128*32];
    const int tid = threadIdx.x;
    const int w = tid>>6, lane = tid&63;
    const int wm = w>>1, wn = w&1;
    const int r0 = by*128, c0 = bx*128;

    const u16* ga[2]; const u16* gb[2]; u16 *la[2], *lb[2];
    #pragma unroll
    for (int i=0;i<2;i++){
        ga[i] = A  + (size_t)(r0 + w*32 + i*16 + (lane>>2))*512 + (lane&3)*8;
        gb[i] = Bt + (size_t)(c0 + w*32 + i*16 + (lane>>2))*512 + (lane&3)*8;
        la[i] = As + w*1024 + i*512;
        lb[i] = Bs + w*1024 + i*512;
    }
    const int lr = lane&15, lk = lane>>4;
    const int ao = (wm*64 + lr)*32 + lk*8;
    const int bo = (wn*64 + lr)*32 + lk*8;

    f32x4 acc[4][4] = {};
    for (int k0=0; k0<512; k0+=32){
        gl_lds16(ga[0]+k0, la[0]); gl_lds16(ga[1]+k0, la[1]);
        gl_lds16(gb[0]+k0, lb[0]); gl_lds16(gb[1]+k0, lb[1]);
        __syncthreads();
        bf16x8 af[4], bfr[4];
        #pragma unroll
        for (int m=0;m<4;m++) af[m]  = *(const bf16x8*)&As[ao + m*512];
        #pragma unroll
        for (int n=0;n<4;n++) bfr[n] = *(const bf16x8*)&Bs[bo + n*512];
        #pragma unroll
        for (int m=0;m<4;m++)
            #pragma unroll
            for (int n=0;n<4;n++)
                acc[m][n] = __builtin_amdgcn_mfma_f32_16x16x32_bf16(af[m], bfr[n], acc[m][n], 0,0,0);
        __syncthreads();
    }
    const float rs = rs_p[0];
    #pragma unroll
    for (int n=0;n<4;n++){
        int col = c0 + wn*64 + n*16 + lr;
        #pragma unroll
        for (int m=0;m<4;m++){
            int row = r0 + wm*64 + m*16 + lk*4;
            #pragma unroll
            for (int r=0;r<4;r++){
                size_t idx = (size_t)(row+r)*1024 + col;
                O[idx] = X[idx] + rs*acc[m][n][r];
            }
        }
    }
}

// ---------------------------------------------------------------------------
// S1: per-segment aggregates. grid (SEG, B), block 128 (thread = k). C1 bf16.
// ---------------------------------------------------------------------------
__global__ __launch_bounds__(128) void k_s1(
    const u16* __restrict__ C1,
    const float* __restrict__ omega_base,
    float* __restrict__ Ag, float* __restrict__ Br, float* __restrict__ Bi)
{
    const int k = threadIdx.x;
    const int seg = blockIdx.x, b = blockIdx.y;
    const float ob = omega_base[k];
    const int n0 = seg*SLEN;
    float aag = 1.f, br = 0.f, bi = 0.f;
    #pragma unroll 4
    for (int s=0; s<SLEN; s++){
        const int n = n0 + s;
        const u16* row = C1 + (size_t)(b*2048+n)*896;
        float Ar = b2f(row[k]);
        float Om = b2f(row[128+k]);
        float Ph = b2f(row[256+k]);
        float Ga = b2f(row[384+k]);
        float alpha = sigmoidf_(Ga);
        float A = fminf(softplusf_(Ar), 3.0f);
        float omega = fminf(fmaxf(sigmoidf_(Om)*PI_F + ob, 1e-4f), PI_F-1e-4f);
        float phi = tanhpi_(Ph);
        float pos = __logf(1.f + (float)n);
        float sa, ca; fsincos(fmaf(omega, pos, phi), &sa, &ca);
        float drive = (1.f-alpha)*A;
        aag *= alpha;
        br = fmaf(alpha, br, drive*ca);
        bi = fmaf(alpha, bi, drive*sa);
    }
    const size_t o = (size_t)(b*SEG + seg)*128 + k;
    Ag[o] = aag; Br[o] = br; Bi[o] = bi;
}

// ---------------------------------------------------------------------------
// S2: serial scan over SEG aggregates per (b,k) channel; writes entry prefix.
// ---------------------------------------------------------------------------
__global__ __launch_bounds__(256) void k_s2(
    const float* __restrict__ Ag, const float* __restrict__ Br, const float* __restrict__ Bi,
    float* __restrict__ Pr, float* __restrict__ Pi)
{
    const int gid = blockIdx.x*256 + threadIdx.x;   // 0..1023
    const int b = gid >> 7, k = gid & 127;
    float pr = 0.f, pi = 0.f;
    #pragma unroll 8
    for (int seg=0; seg<SEG; seg++){
        const size_t o = (size_t)(b*SEG + seg)*128 + k;
        float a = Ag[o], r = Br[o], i = Bi[o];
        Pr[o] = pr; Pi[o] = pi;
        pr = fmaf(a, pr, r);
        pi = fmaf(a, pi, i);
    }
}

// ---------------------------------------------------------------------------
// S3: prefix replay + full post-scan elementwise + neighbor-k cross via LDS,
// writes F bf16 [16384 x 512]. C1 bf16.
// ---------------------------------------------------------------------------
__global__ __launch_bounds__(128) void k_s3(
    const u16* __restrict__ C1,
    const float* __restrict__ omega_base,
    const float* __restrict__ lam_p,
    const float* __restrict__ Pr, const float* __restrict__ Pi,
    u16* __restrict__ F)
{
    const int k = threadIdx.x;
    const int seg = blockIdx.x, b = blockIdx.y;
    const float ob = omega_base[k];
    const float lam = lam_p[0];
    __shared__ float sre[2][129], sim[2][129];

    const size_t po = (size_t)(b*SEG + seg)*128 + k;
    float rr = Pr[po], ri = Pi[po];
    const int n0 = seg*SLEN;

    #pragma unroll 2
    for (int s=0; s<SLEN; s++){
        const int n = n0 + s;
        const u16* row = C1 + (size_t)(b*2048+n)*896;
        float Ar = b2f(row[k]);
        float Om = b2f(row[128+k]);
        float Ph = b2f(row[256+k]);
        float Ga = b2f(row[384+k]);
        float Go = b2f(row[512+k]);
        float Be = b2f(row[640+k]);
        float pq = b2f(row[768+k]);
        float alpha = sigmoidf_(Ga);
        float A = fminf(softplusf_(Ar), 3.0f);
        float omega = fminf(fmaxf(sigmoidf_(Om)*PI_F + ob, 1e-4f), PI_F-1e-4f);
        float phi = tanhpi_(Ph);
        float pos = __logf(1.f + (float)n);
        float sa, ca; fsincos(fmaf(omega, pos, phi), &sa, &ca);
        float drive = (1.f-alpha)*A;
        rr = fmaf(alpha, rr, drive*ca);
        ri = fmaf(alpha, ri, drive*sa);
        float readout = rr*ca + ri*sa;
        float beta = sigmoidf_(Be);
        float r2r = rr - beta*readout*ca;
        float r2i = ri - beta*readout*sa;
        float m2 = r2r*r2r + r2i*r2i + 1e-8f;
        float inv = fminf(rsqrtf(m2), 1.0f);       // 1/max(sqrt(m2),1)
        r2r *= inv; r2i *= inv;
        float rho_re =  r2r*ca + r2i*sa;
        float rho_im = -r2r*sa + r2i*ca;
        float rho2 = rho_re*rho_re + rho_im*rho_im + 1e-6f;
        float spq, cpq; fsincos(pq, &spq, &cpq);
        float align = (rho_re*cpq + rho_im*spq)*rsqrtf(rho2);
        float gate = sigmoidf_(lam*align);
        rho_re *= gate; rho_im *= gate;
        float go = sigmoidf_(Go);

        const int buf = s & 1;
        sre[buf][k] = rho_re; sim[buf][k] = rho_im;
        __syncthreads();

        u16* frow = F + (size_t)(b*2048+n)*512;
        frow[k]       = f2bf(go*rho_re);
        frow[128 + k] = f2bf(go*rho_im);
        if (k < 127){
            float nre = sre[buf][k+1], nim = sim[buf][k+1];
            frow[256 + k] = f2bf(rho_re*nre + rho_im*nim);
            frow[383 + k] = f2bf(rho_im*nre - rho_re*nim);
        } else {
            frow[510] = 0; frow[511] = 0;
        }
    }
}

extern "C" void kernel_launch(void* const* d_in, const int* in_sizes, int n_in,
                              void* d_out, int out_size, void* d_ws, size_t ws_size,
                              hipStream_t stream)
{
    const float* x   = (const float*)d_in[0];
    const float* Wp  = (const float*)d_in[1];
    const float* bp  = (const float*)d_in[2];
    const float* ob  = (const float*)d_in[3];
    const float* Wph = (const float*)d_in[4];
    const float* bph = (const float*)d_in[5];
    const float* Wr  = (const float*)d_in[6];
    const float* lam = (const float*)d_in[7];
    const float* rs  = (const float*)d_in[8];
    float* out = (float*)d_out;

    char* ws = (char*)d_ws;
    // layout (bytes) — offsets kept from R3 (C1 shrank to bf16 in place):
    //   [0, 29360128)            C1 bf16 16384x896
    //   [58720256, +33554432)    Xb bf16 (dead after mm1) -> aliased by:
    //        +0        Ag 512KB, +524288 Br, +1048576 Bi, +1572864 Pr, +2097152 Pi
    //        +2621440  F bf16 16384x512 (16.78MB)
    //   [92274688, +1835008)     Wt bf16 896x1024
    //   [94109696, +1048576)     Wrt bf16 1024x512
    u16*   C1  = (u16*)  (ws + 0);
    u16*   Xb  = (u16*)  (ws + 58720256);
    float* Ag  = (float*)(ws + 58720256);
    float* Brr = (float*)(ws + 58720256 +  524288);
    float* Bii = (float*)(ws + 58720256 + 1048576);
    float* Pr  = (float*)(ws + 58720256 + 1572864);
    float* Pi  = (float*)(ws + 58720256 + 2097152);
    u16*   F   = (u16*)  (ws + 58720256 + 2621440);
    u16*   Wt  = (u16*)  (ws + 92274688);
    u16*   Wrt = (u16*)  (ws + 94109696);

    dim3 blk(256);
    hipLaunchKernelGGL(k_cvt_x, dim3(8192),   blk, 0, stream, x, Xb);
    hipLaunchKernelGGL(k_tcvt,  dim3(24,32),  blk, 0, stream, Wp,  Wt,            1024, 768,  1024);
    hipLaunchKernelGGL(k_tcvt,  dim3(4,32),   blk, 0, stream, Wph, Wt + 768*1024, 1024, 128,  1024);
    hipLaunchKernelGGL(k_tcvt,  dim3(32,16),  blk, 0, stream, Wr,  Wrt,           510,  1024, 512);
    hipLaunchKernelGGL(k_mm1,   dim3(896),    blk, 0, stream, Xb, Wt, bp, bph, C1);
    hipLaunchKernelGGL(k_s1,    dim3(SEG,8),  dim3(128), 0, stream, C1, ob, Ag, Brr, Bii);
    hipLaunchKernelGGL(k_s2,    dim3(4),      blk, 0, stream, Ag, Brr, Bii, Pr, Pi);
    hipLaunchKernelGGL(k_s3,    dim3(SEG,8),  dim3(128), 0, stream, C1, ob, lam, Pr, Pi, F);
    hipLaunchKernelGGL(k_mm2,   dim3(1024),   blk, 0, stream, F, Wrt, x, rs, out);
}